// Round 1
// baseline (8418.922 us; speedup 1.0000x reference)
//
#include <hip/hip_runtime.h>
#include <cstdint>
#include <cstddef>

#define NCLS 32000
#define EMBD 512
#define HIDD 1024
#define BATCH 64
#define SEQL 256
#define NWG 256
#define K0 1536
#define K1 2048
#define K0P (K0 + 8)
#define K1P (K1 + 8)

typedef __attribute__((ext_vector_type(8))) short short8;
typedef __attribute__((ext_vector_type(4))) float float4v;

// ---- workspace layout (bytes) ----
#define WS_BAR   0                       // bar at +0, gen at +64
#define WS_H0    256                     // 2 * 64*1024 * 2B = 262144
#define WS_H1    (WS_H0 + 262144)
#define WS_H1T   (WS_H1 + 262144)        // 1024*64*4 = 262144 (fp32, [k][b])
#define WS_XEMB  (WS_H1T + 262144)       // 256*64*512*2 = 16777216

#define SMEM_BYTES (((16 * K0P + 16 * K1P) * 2) + ((4096 + 32 + 512) * 4))

__device__ __forceinline__ unsigned short f2bf(float f) {
  union { float f; uint32_t u; } x; x.f = f;
  uint32_t r = x.u + 0x7FFFu + ((x.u >> 16) & 1u);
  return (unsigned short)(r >> 16);
}

__device__ __forceinline__ float sigm(float x) {
  return 1.0f / (1.0f + __expf(-x));
}

// sense-free generation barrier across all 256 resident workgroups
__device__ __forceinline__ void gbar(unsigned* bar, unsigned* gen, unsigned target) {
  __syncthreads();
  if (threadIdx.x == 0) {
    __builtin_amdgcn_fence(__ATOMIC_RELEASE, "agent");   // make h stores visible (L2 wb)
    unsigned prev = __hip_atomic_fetch_add(bar, 1u, __ATOMIC_RELAXED, __HIP_MEMORY_SCOPE_AGENT);
    if (prev == NWG - 1) {
      __hip_atomic_store(bar, 0u, __ATOMIC_RELAXED, __HIP_MEMORY_SCOPE_AGENT);
      __hip_atomic_store(gen, target, __ATOMIC_RELEASE, __HIP_MEMORY_SCOPE_AGENT);
    } else {
      while (__hip_atomic_load(gen, __ATOMIC_RELAXED, __HIP_MEMORY_SCOPE_AGENT) < target)
        __builtin_amdgcn_s_sleep(2);
    }
    __builtin_amdgcn_fence(__ATOMIC_ACQUIRE, "agent");   // invalidate stale lines
  }
  __syncthreads();
}

__global__ void init_bar_k(char* ws) {
  if (threadIdx.x < 32) ((unsigned*)(ws + WS_BAR))[threadIdx.x] = 0u;
}

// gather embeddings -> bf16 xemb[t][b][e]
__global__ void embed_k(const int* __restrict__ X, const float* __restrict__ Cemb,
                        char* __restrict__ ws) {
  uint32_t p = blockIdx.x * 256u + threadIdx.x;   // pair index, total 256*64*256 = 4194304
  uint32_t t = p >> 14;
  uint32_t r = p & 16383u;
  uint32_t b = r >> 8;
  uint32_t e2 = r & 255u;
  int row = X[b * SEQL + t];
  const float2 v = *(const float2*)(Cemb + (size_t)row * EMBD + (size_t)e2 * 2);
  uint32_t lo = f2bf(v.x), hi = f2bf(v.y);
  ((uint32_t*)(ws + WS_XEMB))[p] = (hi << 16) | lo;
}

__global__ __launch_bounds__(256, 1)
void lstm_k(const float* __restrict__ Wi0, const float* __restrict__ Wc0,
            const float* __restrict__ Wf0, const float* __restrict__ Wo0,
            const float* __restrict__ Wi1, const float* __restrict__ Wc1,
            const float* __restrict__ Wf1, const float* __restrict__ Wo1,
            const float* __restrict__ bi0, const float* __restrict__ bc0,
            const float* __restrict__ bf0, const float* __restrict__ bo0,
            const float* __restrict__ bi1, const float* __restrict__ bc1,
            const float* __restrict__ bf1, const float* __restrict__ bo1,
            char* ws) {
  const int wg   = blockIdx.x;
  const int tid  = threadIdx.x;
  const int lane = tid & 63;
  const int wv   = tid >> 6;
  const int l15  = lane & 15;
  const int quad = lane >> 4;

  extern __shared__ char smem[];
  unsigned short* w0 = (unsigned short*)smem;        // [16][K0P] bf16
  unsigned short* w1 = w0 + 16 * K0P;                // [16][K1P] bf16
  float* red  = (float*)(w1 + 16 * K1P);             // [4 waves][64 b][16 n]
  float* bias = red + 4096;                          // [32]
  float* cst  = bias + 32;                           // [512]: L0 then L1

  unsigned short* h0buf = (unsigned short*)(ws + WS_H0);
  unsigned short* h1buf = (unsigned short*)(ws + WS_H1);
  float* h1t = (float*)(ws + WS_H1T);
  const unsigned short* xemb = (const unsigned short*)(ws + WS_XEMB);
  unsigned* bar = (unsigned*)(ws + WS_BAR);
  unsigned* gen = bar + 16;

  // ---- stage weights into LDS as bf16, layout [n = jl*4+g][k contiguous] ----
  {
    const float* W0g[4] = {Wi0, Wc0, Wf0, Wo0};
    const float* W1g[4] = {Wi1, Wc1, Wf1, Wo1};
    int jl = tid & 3;
    int kr = tid >> 2;            // 0..63
    int jg = wg * 4 + jl;
    for (int g = 0; g < 4; ++g) {
      unsigned short* dst0 = w0 + (jl * 4 + g) * K0P;
      const float* s0 = W0g[g] + jg;
      for (int k = kr; k < K0; k += 64) dst0[k] = f2bf(s0[(size_t)k * HIDD]);
      unsigned short* dst1 = w1 + (jl * 4 + g) * K1P;
      const float* s1 = W1g[g] + jg;
      for (int k = kr; k < K1; k += 64) dst1[k] = f2bf(s1[(size_t)k * HIDD]);
    }
  }
  if (tid < 16) {
    int jl = tid >> 2, g = tid & 3;
    const float* B0g[4] = {bi0, bc0, bf0, bo0};
    const float* B1g[4] = {bi1, bc1, bf1, bo1};
    bias[tid]      = B0g[g][wg * 4 + jl];
    bias[16 + tid] = B1g[g][wg * 4 + jl];
  }
  cst[tid] = 0.f;
  cst[256 + tid] = 0.f;
  {
    int b = tid >> 2, jl = tid & 3;
    h0buf[b * HIDD + wg * 4 + jl] = 0;   // zero h state, buffer 0
    h1buf[b * HIDD + wg * 4 + jl] = 0;
  }

  unsigned tgt = 0;
  gbar(bar, gen, ++tgt);

  // pipelined phases: phase p runs L0(step p) and L1(step p-1); ONE grid barrier/phase
  for (int p = 0; p <= SEQL; ++p) {
    // ---------- layer 0, step p ----------
    if (p < SEQL) {
      const unsigned short* hp = h0buf + (size_t)(p & 1) * BATCH * HIDD;
      const unsigned short* xe = xemb + (size_t)p * BATCH * EMBD;
      float4v acc0 = {0.f, 0.f, 0.f, 0.f}, acc1 = acc0, acc2 = acc0, acc3 = acc0;
      const int kbeg = wv * 384;   // K-split across 4 waves
      for (int i = 0; i < 12; ++i) {
        int k0 = kbeg + i * 32;
        short8 bfr = *(const short8*)(w0 + l15 * K0P + k0 + quad * 8);
        const unsigned short* as;
        int koff, stride;
        if (k0 < HIDD) { as = hp; koff = k0; stride = HIDD; }
        else           { as = xe; koff = k0 - HIDD; stride = EMBD; }
        const unsigned short* ab = as + koff + quad * 8 + l15 * stride;
        short8 a0 = *(const short8*)(ab);
        short8 a1 = *(const short8*)(ab + 16 * stride);
        short8 a2 = *(const short8*)(ab + 32 * stride);
        short8 a3 = *(const short8*)(ab + 48 * stride);
        acc0 = __builtin_amdgcn_mfma_f32_16x16x32_bf16(a0, bfr, acc0, 0, 0, 0);
        acc1 = __builtin_amdgcn_mfma_f32_16x16x32_bf16(a1, bfr, acc1, 0, 0, 0);
        acc2 = __builtin_amdgcn_mfma_f32_16x16x32_bf16(a2, bfr, acc2, 0, 0, 0);
        ac3: ;
        acc3 = __builtin_amdgcn_mfma_f32_16x16x32_bf16(a3, bfr, acc3, 0, 0, 0);
      }
      float* rw = red + wv * 1024 + quad * 64 + l15;
      #pragma unroll
      for (int r = 0; r < 4; ++r) {
        rw[r * 16]       = acc0[r];
        rw[256 + r * 16] = acc1[r];
        rw[512 + r * 16] = acc2[r];
        rw[768 + r * 16] = acc3[r];
      }
    }
    __syncthreads();
    if (p < SEQL) {
      int b = tid >> 2, jl = tid & 3;
      const float* rr = red + b * 16 + jl * 4;
      float4v v = *(const float4v*)rr;
      v += *(const float4v*)(rr + 1024);
      v += *(const float4v*)(rr + 2048);
      v += *(const float4v*)(rr + 3072);
      float ig = sigm(v.x + bias[jl * 4 + 0]);
      float gg = tanhf(v.y + bias[jl * 4 + 1]);
      float fg = sigm(v.z + bias[jl * 4 + 2]);
      float og = sigm(v.w + bias[jl * 4 + 3]);
      float c = fg * cst[tid] + ig * gg;
      cst[tid] = c;
      float h = og * tanhf(c);
      h0buf[(size_t)((p & 1) ^ 1) * BATCH * HIDD + b * HIDD + wg * 4 + jl] = f2bf(h);
    }
    __syncthreads();
    // ---------- layer 1, step p-1 ----------
    if (p >= 1) {
      const int t1 = p - 1;
      const unsigned short* h1p = h1buf + (size_t)(t1 & 1) * BATCH * HIDD;
      const unsigned short* h0c = h0buf + (size_t)((t1 & 1) ^ 1) * BATCH * HIDD;
      float4v acc0 = {0.f, 0.f, 0.f, 0.f}, acc1 = acc0, acc2 = acc0, acc3 = acc0;
      const int kbeg = wv * 512;
      for (int i = 0; i < 16; ++i) {
        int k0 = kbeg + i * 32;
        short8 bfr = *(const short8*)(w1 + l15 * K1P + k0 + quad * 8);
        const unsigned short* as;
        int koff;
        if (k0 < HIDD) { as = h1p; koff = k0; }
        else           { as = h0c; koff = k0 - HIDD; }
        const unsigned short* ab = as + koff + quad * 8 + l15 * HIDD;
        short8 a0 = *(const short8*)(ab);
        short8 a1 = *(const short8*)(ab + 16 * HIDD);
        short8 a2 = *(const short8*)(ab + 32 * HIDD);
        short8 a3 = *(const short8*)(ab + 48 * HIDD);
        acc0 = __builtin_amdgcn_mfma_f32_16x16x32_bf16(a0, bfr, acc0, 0, 0, 0);
        acc1 = __builtin_amdgcn_mfma_f32_16x16x32_bf16(a1, bfr, acc1, 0, 0, 0);
        acc2 = __builtin_amdgcn_mfma_f32_16x16x32_bf16(a2, bfr, acc2, 0, 0, 0);
        acc3 = __builtin_amdgcn_mfma_f32_16x16x32_bf16(a3, bfr, acc3, 0, 0, 0);
      }
      float* rw = red + wv * 1024 + quad * 64 + l15;
      #pragma unroll
      for (int r = 0; r < 4; ++r) {
        rw[r * 16]       = acc0[r];
        rw[256 + r * 16] = acc1[r];
        rw[512 + r * 16] = acc2[r];
        rw[768 + r * 16] = acc3[r];
      }
    }
    __syncthreads();
    if (p >= 1) {
      const int t1 = p - 1;
      int b = tid >> 2, jl = tid & 3;
      const float* rr = red + b * 16 + jl * 4;
      float4v v = *(const float4v*)rr;
      v += *(const float4v*)(rr + 1024);
      v += *(const float4v*)(rr + 2048);
      v += *(const float4v*)(rr + 3072);
      float ig = sigm(v.x + bias[16 + jl * 4 + 0]);
      float gg = tanhf(v.y + bias[16 + jl * 4 + 1]);
      float fg = sigm(v.z + bias[16 + jl * 4 + 2]);
      float og = sigm(v.w + bias[16 + jl * 4 + 3]);
      float c = fg * cst[256 + tid] + ig * gg;
      cst[256 + tid] = c;
      float h = og * tanhf(c);
      h1buf[(size_t)((t1 & 1) ^ 1) * BATCH * HIDD + b * HIDD + wg * 4 + jl] = f2bf(h);
      if (t1 == SEQL - 1) h1t[(wg * 4 + jl) * 64 + b] = h;   // fp32 [k][b] for logits
    }
    gbar(bar, gen, ++tgt);
  }
}

// logits: out[b][n] = sum_k h1[b][k] * Wout[k][n] + bout[n]
__global__ void out_gemm_k(const char* __restrict__ ws, const float* __restrict__ Wout,
                           const float* __restrict__ bout, float* __restrict__ out) {
  const float* h1t = (const float*)(ws + WS_H1T);   // [1024][64], wave-uniform reads
  int n = blockIdx.x * 128 + threadIdx.x;           // grid 250 * 128 = 32000
  float acc[BATCH];
  #pragma unroll
  for (int b = 0; b < BATCH; ++b) acc[b] = 0.f;
  #pragma unroll 2
  for (int k = 0; k < HIDD; ++k) {
    float w = Wout[(size_t)k * NCLS + n];
    const float* hv = h1t + k * 64;
    #pragma unroll
    for (int b = 0; b < BATCH; ++b) acc[b] = fmaf(w, hv[b], acc[b]);
  }
  float bb = bout[n];
  #pragma unroll
  for (int b = 0; b < BATCH; ++b) out[(size_t)b * NCLS + n] = acc[b] + bb;
}

extern "C" void kernel_launch(void* const* d_in, const int* in_sizes, int n_in,
                              void* d_out, int out_size, void* d_ws, size_t ws_size,
                              hipStream_t stream) {
  const int*   X    = (const int*)d_in[0];
  const float* Cemb = (const float*)d_in[1];
  const float* Wi0  = (const float*)d_in[2];
  const float* bi0  = (const float*)d_in[3];
  const float* Wc0  = (const float*)d_in[4];
  const float* bc0  = (const float*)d_in[5];
  const float* Wf0  = (const float*)d_in[6];
  const float* bf0  = (const float*)d_in[7];
  const float* Wo0  = (const float*)d_in[8];
  const float* bo0  = (const float*)d_in[9];
  const float* Wi1  = (const float*)d_in[10];
  const float* bi1  = (const float*)d_in[11];
  const float* Wc1  = (const float*)d_in[12];
  const float* bc1  = (const float*)d_in[13];
  const float* Wf1  = (const float*)d_in[14];
  const float* bf1  = (const float*)d_in[15];
  const float* Wo1  = (const float*)d_in[16];
  const float* bo1  = (const float*)d_in[17];
  const float* Wout = (const float*)d_in[18];
  const float* bout = (const float*)d_in[19];
  float* out = (float*)d_out;
  char* ws = (char*)d_ws;

  static bool attr_set = false;
  if (!attr_set) {
    hipFuncSetAttribute((const void*)lstm_k,
                        hipFuncAttributeMaxDynamicSharedMemorySize, SMEM_BYTES);
    attr_set = true;
  }

  init_bar_k<<<1, 64, 0, stream>>>(ws);
  embed_k<<<16384, 256, 0, stream>>>(X, Cemb, ws);
  lstm_k<<<NWG, 256, SMEM_BYTES, stream>>>(Wi0, Wc0, Wf0, Wo0, Wi1, Wc1, Wf1, Wo1,
                                           bi0, bc0, bf0, bo0, bi1, bc1, bf1, bo1, ws);
  out_gemm_k<<<250, 128, 0, stream>>>(ws, Wout, bout, out);
}

// Round 2
// 5269.212 us; speedup vs baseline: 1.5978x; 1.5978x over previous
//
#include <hip/hip_runtime.h>
#include <cstdint>
#include <cstddef>

#define NCLS 32000
#define EMBD 512
#define HIDD 1024
#define BATCH 64
#define SEQL 256
#define NWG 256
#define K0 1536
#define K1 2048
#define K0P (K0 + 8)
#define K1P (K1 + 8)
#define BH (BATCH * HIDD)

typedef __attribute__((ext_vector_type(8))) short short8;
typedef __attribute__((ext_vector_type(4))) float float4v;

// ---- workspace layout (bytes) ----
#define WS_BAR   0                       // bar at +0 (monotonic), gen at +64
#define WS_H0    256                     // 2 * 64*1024 * 2B = 262144 (double-buffered, bf16 [b][k])
#define WS_H1    (WS_H0 + 2*BH*2)
#define WS_XEMB  (WS_H1 + 2*BH*2)        // 256*64*512*2 = 16777216

#define SMEM_BYTES ((16*K0P + 16*K1P)*2 + (8192 + 32 + 512)*4)

__device__ __forceinline__ unsigned short f2bf(float f) {
  union { float f; uint32_t u; } x; x.f = f;
  uint32_t r = x.u + 0x7FFFu + ((x.u >> 16) & 1u);
  return (unsigned short)(r >> 16);
}

__device__ __forceinline__ float sigm(float x) {
  return 1.0f / (1.0f + __expf(-x));
}

// Monotonic grid barrier. All shared data is written with agent-scope (sc1)
// relaxed atomic stores, so release needs only the vmcnt drain that
// __syncthreads already performs (no buffer_wbl2). Acquire = buffer_inv sc1.
__device__ __forceinline__ void gbar(unsigned* bar, unsigned* gen, unsigned target) {
  __syncthreads();   // drains each wave's vmcnt before s_barrier -> all sc1 stores visible
  if (threadIdx.x == 0) {
    unsigned prev = __hip_atomic_fetch_add(bar, 1u, __ATOMIC_RELAXED, __HIP_MEMORY_SCOPE_AGENT);
    if (prev == target * NWG - 1u) {
      __hip_atomic_store(gen, target, __ATOMIC_RELAXED, __HIP_MEMORY_SCOPE_AGENT);
    } else {
      while (__hip_atomic_load(gen, __ATOMIC_RELAXED, __HIP_MEMORY_SCOPE_AGENT) < target)
        __builtin_amdgcn_s_sleep(1);
    }
    asm volatile("buffer_inv sc1\n\ts_waitcnt vmcnt(0)" ::: "memory");
  }
  __syncthreads();
}

__global__ void init_bar_k(char* ws) {
  if (threadIdx.x < 32) ((unsigned*)(ws + WS_BAR))[threadIdx.x] = 0u;
}

// gather embeddings -> bf16 xemb[t][b][e]
__global__ void embed_k(const int* __restrict__ X, const float* __restrict__ Cemb,
                        char* __restrict__ ws) {
  uint32_t p = blockIdx.x * 256u + threadIdx.x;   // pair index, 256*64*256 = 4194304
  uint32_t t = p >> 14;
  uint32_t r = p & 16383u;
  uint32_t b = r >> 8;
  uint32_t e2 = r & 255u;
  int row = X[b * SEQL + t];
  const float2 v = *(const float2*)(Cemb + (size_t)row * EMBD + (size_t)e2 * 2);
  uint32_t lo = f2bf(v.x), hi = f2bf(v.y);
  ((uint32_t*)(ws + WS_XEMB))[p] = (hi << 16) | lo;
}

__global__ __launch_bounds__(512, 1)
void lstm_k(const float* __restrict__ Wi0, const float* __restrict__ Wc0,
            const float* __restrict__ Wf0, const float* __restrict__ Wo0,
            const float* __restrict__ Wi1, const float* __restrict__ Wc1,
            const float* __restrict__ Wf1, const float* __restrict__ Wo1,
            const float* __restrict__ bi0, const float* __restrict__ bc0,
            const float* __restrict__ bf0, const float* __restrict__ bo0,
            const float* __restrict__ bi1, const float* __restrict__ bc1,
            const float* __restrict__ bf1, const float* __restrict__ bo1,
            char* ws) {
  const int wg   = blockIdx.x;
  const int tid  = threadIdx.x;
  const int lane = tid & 63;
  const int wv   = tid >> 6;        // 0..7
  const int l15  = lane & 15;
  const int quad = lane >> 4;

  extern __shared__ char smem[];
  unsigned short* w0 = (unsigned short*)smem;        // [16][K0P] bf16
  unsigned short* w1 = w0 + 16 * K0P;                // [16][K1P] bf16
  float* red  = (float*)(w1 + 16 * K1P);             // [8 waves][64 b][16 n]
  float* bias = red + 8192;                          // [32]
  float* cst  = bias + 32;                           // [512]: tid<256 L0, tid>=256 L1

  unsigned short* h0buf = (unsigned short*)(ws + WS_H0);
  unsigned short* h1buf = (unsigned short*)(ws + WS_H1);
  const unsigned short* xemb = (const unsigned short*)(ws + WS_XEMB);
  unsigned* bar = (unsigned*)(ws + WS_BAR);
  unsigned* gen = bar + 16;

  // ---- stage weights into LDS as bf16, layout [n = jl*4+g][k contiguous] ----
  {
    const float* W0g[4] = {Wi0, Wc0, Wf0, Wo0};
    const float* W1g[4] = {Wi1, Wc1, Wf1, Wo1};
    int jl = tid & 3;
    int kr = tid >> 2;            // 0..127
    int jg = wg * 4 + jl;
    for (int g = 0; g < 4; ++g) {
      unsigned short* dst0 = w0 + (jl * 4 + g) * K0P;
      const float* s0 = W0g[g] + jg;
      for (int k = kr; k < K0; k += 128) dst0[k] = f2bf(s0[(size_t)k * HIDD]);
      unsigned short* dst1 = w1 + (jl * 4 + g) * K1P;
      const float* s1 = W1g[g] + jg;
      for (int k = kr; k < K1; k += 128) dst1[k] = f2bf(s1[(size_t)k * HIDD]);
    }
  }
  if (tid < 32) {
    const float* B0g[4] = {bi0, bc0, bf0, bo0};
    const float* B1g[4] = {bi1, bc1, bf1, bo1};
    int lay = tid >> 4, idx = tid & 15, jl = idx >> 2, g = idx & 3;
    bias[tid] = (lay ? B1g[g] : B0g[g])[wg * 4 + jl];
  }
  cst[tid] = 0.f;
  if (tid < 128) {   // zero h state (buffer 0) via agent-coherent stores
    unsigned short* base = (tid < 64) ? h0buf : h1buf;
    int b = tid & 63;
    __hip_atomic_store((unsigned long long*)(base + (size_t)b * HIDD + wg * 4), 0ull,
                       __ATOMIC_RELAXED, __HIP_MEMORY_SCOPE_AGENT);
  }

  unsigned tgt = 0;
  gbar(bar, gen, ++tgt);

  // phase p: waves 0-3 run L0(step p), waves 4-7 run L1(step p-1), concurrently.
  for (int p = 0; p <= SEQL; ++p) {
    const int run0 = (p < SEQL);
    const int run1 = (p >= 1);
    if (wv < 4) {
      if (run0) {
        const unsigned short* hp = h0buf + (size_t)(p & 1) * BH;        // h0(p-1)
        const unsigned short* xe = xemb + (size_t)p * BATCH * EMBD;
        float4v acc0 = {0.f,0.f,0.f,0.f}, acc1 = acc0, acc2 = acc0, acc3 = acc0;
        const int kbeg = wv * 384;
        for (int i = 0; i < 12; ++i) {
          int k0 = kbeg + i * 32;
          short8 bfr = *(const short8*)(w0 + l15 * K0P + k0 + quad * 8);
          const unsigned short* as; int koff, stride;
          if (k0 < HIDD) { as = hp; koff = k0; stride = HIDD; }
          else           { as = xe; koff = k0 - HIDD; stride = EMBD; }
          const unsigned short* ab = as + koff + quad * 8 + (size_t)l15 * stride;
          short8 f0 = *(const short8*)(ab);
          short8 f1 = *(const short8*)(ab + 16 * stride);
          short8 f2 = *(const short8*)(ab + 32 * stride);
          short8 f3 = *(const short8*)(ab + 48 * stride);
          acc0 = __builtin_amdgcn_mfma_f32_16x16x32_bf16(f0, bfr, acc0, 0, 0, 0);
          acc1 = __builtin_amdgcn_mfma_f32_16x16x32_bf16(f1, bfr, acc1, 0, 0, 0);
          acc2 = __builtin_amdgcn_mfma_f32_16x16x32_bf16(f2, bfr, acc2, 0, 0, 0);
          acc3 = __builtin_amdgcn_mfma_f32_16x16x32_bf16(f3, bfr, acc3, 0, 0, 0);
        }
        float* rw = red + wv * 1024 + quad * 64 + l15;
        #pragma unroll
        for (int r = 0; r < 4; ++r) {
          rw[r * 16]       = acc0[r];
          rw[256 + r * 16] = acc1[r];
          rw[512 + r * 16] = acc2[r];
          rw[768 + r * 16] = acc3[r];
        }
      }
    } else {
      if (run1) {
        const unsigned short* h1p = h1buf + (size_t)((p & 1) ^ 1) * BH;  // h1(p-2)
        const unsigned short* h0c = h0buf + (size_t)(p & 1) * BH;        // h0(p-1)
        float4v acc0 = {0.f,0.f,0.f,0.f}, acc1 = acc0, acc2 = acc0, acc3 = acc0;
        const int kbeg = (wv - 4) * 512;
        for (int i = 0; i < 16; ++i) {
          int k0 = kbeg + i * 32;
          short8 bfr = *(const short8*)(w1 + l15 * K1P + k0 + quad * 8);
          const unsigned short* as; int koff;
          if (k0 < HIDD) { as = h1p; koff = k0; }
          else           { as = h0c; koff = k0 - HIDD; }
          const unsigned short* ab = as + koff + quad * 8 + (size_t)l15 * HIDD;
          short8 f0 = *(const short8*)(ab);
          short8 f1 = *(const short8*)(ab + 16 * HIDD);
          short8 f2 = *(const short8*)(ab + 32 * HIDD);
          short8 f3 = *(const short8*)(ab + 48 * HIDD);
          acc0 = __builtin_amdgcn_mfma_f32_16x16x32_bf16(f0, bfr, acc0, 0, 0, 0);
          acc1 = __builtin_amdgcn_mfma_f32_16x16x32_bf16(f1, bfr, acc1, 0, 0, 0);
          acc2 = __builtin_amdgcn_mfma_f32_16x16x32_bf16(f2, bfr, acc2, 0, 0, 0);
          acc3 = __builtin_amdgcn_mfma_f32_16x16x32_bf16(f3, bfr, acc3, 0, 0, 0);
        }
        float* rw = red + wv * 1024 + quad * 64 + l15;
        #pragma unroll
        for (int r = 0; r < 4; ++r) {
          rw[r * 16]       = acc0[r];
          rw[256 + r * 16] = acc1[r];
          rw[512 + r * 16] = acc2[r];
          rw[768 + r * 16] = acc3[r];
        }
      }
    }
    __syncthreads();
    // split epilogue: tid<256 -> L0 gates+publish, tid>=256 -> L1
    if (tid < 256) {
      if (run0) {
        int b = tid >> 2, jl = tid & 3;
        const float* rr = red + b * 16 + jl * 4;
        float4v v = *(const float4v*)rr;
        v += *(const float4v*)(rr + 1024);
        v += *(const float4v*)(rr + 2048);
        v += *(const float4v*)(rr + 3072);
        float ig = sigm(v.x + bias[jl * 4 + 0]);
        float gg = tanhf(v.y + bias[jl * 4 + 1]);
        float fg = sigm(v.z + bias[jl * 4 + 2]);
        float og = sigm(v.w + bias[jl * 4 + 3]);
        float c = fg * cst[tid] + ig * gg;
        cst[tid] = c;
        unsigned x  = f2bf(og * tanhf(c));
        unsigned x1 = (unsigned)__shfl((int)x, lane + 1);
        unsigned x2 = (unsigned)__shfl((int)x, lane + 2);
        unsigned x3 = (unsigned)__shfl((int)x, lane + 3);
        if ((lane & 3) == 0) {
          unsigned long long val = (unsigned long long)(x | (x1 << 16))
                                 | ((unsigned long long)(x2 | (x3 << 16)) << 32);
          unsigned short* dst = h0buf + (size_t)((p & 1) ^ 1) * BH + (size_t)b * HIDD + wg * 4;
          __hip_atomic_store((unsigned long long*)dst, val,
                             __ATOMIC_RELAXED, __HIP_MEMORY_SCOPE_AGENT);
        }
      }
    } else {
      if (run1) {
        int t = tid - 256, b = t >> 2, jl = t & 3;
        const float* rr = red + 4096 + b * 16 + jl * 4;
        float4v v = *(const float4v*)rr;
        v += *(const float4v*)(rr + 1024);
        v += *(const float4v*)(rr + 2048);
        v += *(const float4v*)(rr + 3072);
        float ig = sigm(v.x + bias[16 + jl * 4 + 0]);
        float gg = tanhf(v.y + bias[16 + jl * 4 + 1]);
        float fg = sigm(v.z + bias[16 + jl * 4 + 2]);
        float og = sigm(v.w + bias[16 + jl * 4 + 3]);
        float c = fg * cst[tid] + ig * gg;
        cst[tid] = c;
        unsigned x  = f2bf(og * tanhf(c));
        unsigned x1 = (unsigned)__shfl((int)x, lane + 1);
        unsigned x2 = (unsigned)__shfl((int)x, lane + 2);
        unsigned x3 = (unsigned)__shfl((int)x, lane + 3);
        if ((lane & 3) == 0) {
          unsigned long long val = (unsigned long long)(x | (x1 << 16))
                                 | ((unsigned long long)(x2 | (x3 << 16)) << 32);
          unsigned short* dst = h1buf + (size_t)(p & 1) * BH + (size_t)b * HIDD + wg * 4;
          __hip_atomic_store((unsigned long long*)dst, val,
                             __ATOMIC_RELAXED, __HIP_MEMORY_SCOPE_AGENT);
        }
      }
    }
    gbar(bar, gen, ++tgt);
  }
  // final h1 (step 255) lands in h1buf buffer 0 -> consumed by out_gemm_k
}

// logits via MFMA: out[b][n] = sum_k h1[b][k] * Wout[k][n] + bout[n]
__global__ __launch_bounds__(256, 1)
void out_gemm_k(const char* __restrict__ ws, const float* __restrict__ Wout,
                const float* __restrict__ bout, float* __restrict__ out) {
  const unsigned short* h1 = (const unsigned short*)(ws + WS_H1);  // bf16 [64][1024], buffer 0
  const int tid = threadIdx.x, lane = tid & 63, wv = tid >> 6;
  const int l15 = lane & 15, quad = lane >> 4;
  const int n0 = blockIdx.x * 128 + wv * 32;
  float4v acc[4][2];
  #pragma unroll
  for (int m = 0; m < 4; ++m)
    #pragma unroll
    for (int f = 0; f < 2; ++f) acc[m][f] = (float4v){0.f, 0.f, 0.f, 0.f};

  for (int k0 = 0; k0 < HIDD; k0 += 32) {
    short8 a[4];
    #pragma unroll
    for (int m = 0; m < 4; ++m)
      a[m] = *(const short8*)(h1 + (size_t)(l15 + 16 * m) * HIDD + k0 + quad * 8);
    short8 bf[2];
    #pragma unroll
    for (int f = 0; f < 2; ++f) {
      int n = n0 + f * 16 + l15;
      #pragma unroll
      for (int j = 0; j < 8; ++j) {
        float w = Wout[(size_t)(k0 + quad * 8 + j) * NCLS + n];
        bf[f][j] = (short)f2bf(w);
      }
    }
    #pragma unroll
    for (int m = 0; m < 4; ++m)
      #pragma unroll
      for (int f = 0; f < 2; ++f)
        acc[m][f] = __builtin_amdgcn_mfma_f32_16x16x32_bf16(a[m], bf[f], acc[m][f], 0, 0, 0);
  }
  #pragma unroll
  for (int m = 0; m < 4; ++m)
    #pragma unroll
    for (int f = 0; f < 2; ++f) {
      int n = n0 + f * 16 + l15;
      float bb = bout[n];
      #pragma unroll
      for (int r = 0; r < 4; ++r) {
        int b = m * 16 + quad * 4 + r;
        out[(size_t)b * NCLS + n] = acc[m][f][r] + bb;
      }
    }
}

extern "C" void kernel_launch(void* const* d_in, const int* in_sizes, int n_in,
                              void* d_out, int out_size, void* d_ws, size_t ws_size,
                              hipStream_t stream) {
  const int*   X    = (const int*)d_in[0];
  const float* Cemb = (const float*)d_in[1];
  const float* Wi0  = (const float*)d_in[2];
  const float* bi0  = (const float*)d_in[3];
  const float* Wc0  = (const float*)d_in[4];
  const float* bc0  = (const float*)d_in[5];
  const float* Wf0  = (const float*)d_in[6];
  const float* bf0  = (const float*)d_in[7];
  const float* Wo0  = (const float*)d_in[8];
  const float* bo0  = (const float*)d_in[9];
  const float* Wi1  = (const float*)d_in[10];
  const float* bi1  = (const float*)d_in[11];
  const float* Wc1  = (const float*)d_in[12];
  const float* bc1  = (const float*)d_in[13];
  const float* Wf1  = (const float*)d_in[14];
  const float* bf1  = (const float*)d_in[15];
  const float* Wo1  = (const float*)d_in[16];
  const float* bo1  = (const float*)d_in[17];
  const float* Wout = (const float*)d_in[18];
  const float* bout = (const float*)d_in[19];
  float* out = (float*)d_out;
  char* ws = (char*)d_ws;

  hipFuncSetAttribute((const void*)lstm_k,
                      hipFuncAttributeMaxDynamicSharedMemorySize, SMEM_BYTES);

  init_bar_k<<<1, 64, 0, stream>>>(ws);
  embed_k<<<16384, 256, 0, stream>>>(X, Cemb, ws);
  lstm_k<<<NWG, 512, SMEM_BYTES, stream>>>(Wi0, Wc0, Wf0, Wo0, Wi1, Wc1, Wf1, Wo1,
                                           bi0, bc0, bf0, bo0, bi1, bc1, bf1, bo1, ws);
  out_gemm_k<<<250, 256, 0, stream>>>(ws, Wout, bout, out);
}